// Round 7
// baseline (563.616 us; speedup 1.0000x reference)
//
#include <hip/hip_runtime.h>

#define LD_   16384
#define LU_   65536
#define N_    8
#define DIN   256
#define DOUT  128
#define K_    3
#define M_    (LD_ * N_)   // 131072 rows through the MLP

typedef short bf16x8 __attribute__((ext_vector_type(8)));
typedef float f32x4  __attribute__((ext_vector_type(4)));
typedef unsigned int u32x4 __attribute__((ext_vector_type(4)));

// fp32 -> bf16 round-to-nearest-even (inputs finite, no NaN handling)
__device__ __forceinline__ unsigned short f2bf(float f) {
    unsigned int x = __float_as_uint(f);
    x += 0x7fffu + ((x >> 16) & 1u);
    return (unsigned short)(x >> 16);
}

__device__ __forceinline__ bf16x8 ld_bf16x8(const unsigned short* p) {
    // two aligned 8 B LDS reads (b64); p is 8 B aligned by construction
    const short4 lo = *(const short4*)p;
    const short4 hi = *(const short4*)(p + 4);
    bf16x8 r = {lo.x, lo.y, lo.z, lo.w, hi.x, hi.y, hi.z, hi.w};
    return r;
}

// LDS strides (bf16 elements); S/2 mod 32 == 2 -> conflict-free b64 frag reads
#define W1_STRIDE 260
#define W2_STRIDE 132
#define H1_STRIDE 132

// h workspace layout (R7): each 128-col row is stored SPLIT-HALF-INTERLEAVED:
// uint4 slot s (s=0..15, 16 B) = cols {4s..4s+3} ++ {64+4s..64+4s+3}.
// This lets the gather read 16 B/lane (quarter-wave = one 256 B row) while
// pairing exactly with two dense f32x4 reads of up (cols 4s.. and 64+4s..).
// MLP writes 4-consecutive-col quads c0 = nt*16+lg*4 -> ushort offset
// (c0&63)*2 + (c0>>6)*4.

// ---------------------------------------------------------------------------
// MLP: h[m,:] = relu(down[m,:] @ W1 + b1) @ W2 + b2, h stored as bf16
// (swizzled layout above). 256 blocks x 512 threads, 4 passes of 128 rows.
// Swapped-operand MFMA (D = W^T . x^T): lane lm = row, regs = 4 consecutive
// output features. Per-wave-private sH -> no per-pass barriers. Down rows
// prefetched across passes; pass-0 loads issued before W staging.
// ---------------------------------------------------------------------------
__global__ __launch_bounds__(512, 2) void knn_mlp_mfma(
    const float* __restrict__ down, const float* __restrict__ W1,
    const float* __restrict__ b1,   const float* __restrict__ W2,
    const float* __restrict__ b2,   unsigned short* __restrict__ h)
{
    __shared__ unsigned short sW1t[DOUT * W1_STRIDE];        // [n][k] 65 KiB
    __shared__ unsigned short sW2t[DOUT * W2_STRIDE];        // [n][k] 33 KiB
    __shared__ unsigned short sH[8][16 * H1_STRIDE];         // per-wave 33 KiB
    __shared__ float sB1[DOUT], sB2[DOUT];                   // 1 KiB

    const int tid  = threadIdx.x;
    const int wave = tid >> 6, lane = tid & 63;
    const int lm = lane & 15, lg = lane >> 4;

    const int row0 = blockIdx.x * 512 + wave * 16;           // pass adds 128
    const float* dbase = down + (size_t)(row0 + lm) * DIN + lg * 8;

    // ---- issue pass-0 row loads FIRST: they fly under the W staging ----
    float4 raw[16];
    #pragma unroll
    for (int k = 0; k < 8; ++k) {
        raw[2 * k]     = *(const float4*)(dbase + k * 32);
        raw[2 * k + 1] = *(const float4*)(dbase + k * 32 + 4);
    }

    // ---- stage W1^T (bf16, transposed) ----
    #pragma unroll
    for (int it = 0; it < 16; ++it) {
        const int fid = it * 512 + tid;              // 8192 float4s of W1
        const int k = fid >> 5, n4 = (fid & 31) * 4;
        const float4 w = ((const float4*)W1)[fid];
        sW1t[(n4 + 0) * W1_STRIDE + k] = f2bf(w.x);
        sW1t[(n4 + 1) * W1_STRIDE + k] = f2bf(w.y);
        sW1t[(n4 + 2) * W1_STRIDE + k] = f2bf(w.z);
        sW1t[(n4 + 3) * W1_STRIDE + k] = f2bf(w.w);
    }
    // ---- stage W2^T ----
    #pragma unroll
    for (int it = 0; it < 8; ++it) {
        const int fid = it * 512 + tid;              // 4096 float4s of W2
        const int k = fid >> 5, n4 = (fid & 31) * 4;
        const float4 w = ((const float4*)W2)[fid];
        sW2t[(n4 + 0) * W2_STRIDE + k] = f2bf(w.x);
        sW2t[(n4 + 1) * W2_STRIDE + k] = f2bf(w.y);
        sW2t[(n4 + 2) * W2_STRIDE + k] = f2bf(w.z);
        sW2t[(n4 + 3) * W2_STRIDE + k] = f2bf(w.w);
    }
    // ---- stage biases (f32, 128 each) ----
    if (tid < 32)      ((float4*)sB1)[tid]      = ((const float4*)b1)[tid];
    else if (tid < 64) ((float4*)sB2)[tid - 32] = ((const float4*)b2)[tid - 32];
    __syncthreads();   // the ONLY workgroup barrier: weights staged

    unsigned short* hw = sH[wave];

    #pragma unroll
    for (int pass = 0; pass < 4; ++pass) {
        const int chunk = row0 + pass * 128;

        // convert in-flight rows to B-frags (down^T); raw regs then free
        bf16x8 A[8];
        #pragma unroll
        for (int k = 0; k < 8; ++k) {
            const float4 r0 = raw[2 * k], r1 = raw[2 * k + 1];
            const bf16x8 a = {(short)f2bf(r0.x), (short)f2bf(r0.y), (short)f2bf(r0.z), (short)f2bf(r0.w),
                              (short)f2bf(r1.x), (short)f2bf(r1.y), (short)f2bf(r1.z), (short)f2bf(r1.w)};
            A[k] = a;
        }

        // issue next pass's 16 loads: they fly under the MFMAs
        if (pass < 3) {
            const float* dp = dbase + (size_t)(pass + 1) * 128 * DIN;
            #pragma unroll
            for (int k = 0; k < 8; ++k) {
                raw[2 * k]     = *(const float4*)(dp + k * 32);
                raw[2 * k + 1] = *(const float4*)(dp + k * 32 + 4);
            }
        }

        // layer 1: D1 = W1^T . down^T  (lane: m=lm, n1=nt*16+lg*4+i)
        f32x4 acc[8];
        #pragma unroll
        for (int nt = 0; nt < 8; ++nt) acc[nt] = (f32x4){0.f, 0.f, 0.f, 0.f};
        #pragma unroll
        for (int k = 0; k < 8; ++k) {
            const int koff = k * 32 + lg * 8;
            #pragma unroll
            for (int nt = 0; nt < 8; ++nt) {
                const bf16x8 Wf = ld_bf16x8(&sW1t[(nt * 16 + lm) * W1_STRIDE + koff]);
                acc[nt] = __builtin_amdgcn_mfma_f32_16x16x32_bf16(Wf, A[k], acc[nt], 0, 0, 0);
            }
        }

        // relu + bias -> per-wave LDS tile, packed ds_write_b64
        #pragma unroll
        for (int nt = 0; nt < 8; ++nt) {
            const float4 bq = *(const float4*)&sB1[nt * 16 + lg * 4];
            ushort4 st;
            st.x = f2bf(fmaxf(acc[nt][0] + bq.x, 0.0f));
            st.y = f2bf(fmaxf(acc[nt][1] + bq.y, 0.0f));
            st.z = f2bf(fmaxf(acc[nt][2] + bq.z, 0.0f));
            st.w = f2bf(fmaxf(acc[nt][3] + bq.w, 0.0f));
            *(ushort4*)&hw[lm * H1_STRIDE + nt * 16 + lg * 4] = st;
        }
        // wave-local write->read ordering on the private sH tile
        asm volatile("s_waitcnt lgkmcnt(0)" ::: "memory");

        // layer 2: D2 = W2^T . h1^T  (lane: m=lm, n2=nt*16+lg*4+i)
        f32x4 acc2[8];
        #pragma unroll
        for (int nt = 0; nt < 8; ++nt) acc2[nt] = (f32x4){0.f, 0.f, 0.f, 0.f};
        #pragma unroll
        for (int ks = 0; ks < 4; ++ks) {
            const int koff = ks * 32 + lg * 8;
            const bf16x8 Bh = ld_bf16x8(&hw[lm * H1_STRIDE + koff]);
            #pragma unroll
            for (int nt = 0; nt < 8; ++nt) {
                const bf16x8 Wf = ld_bf16x8(&sW2t[(nt * 16 + lm) * W2_STRIDE + koff]);
                acc2[nt] = __builtin_amdgcn_mfma_f32_16x16x32_bf16(Wf, Bh, acc2[nt], 0, 0, 0);
            }
        }

        // epilogue: + b2, cvt bf16, packed 8 B stores into the SWIZZLED
        // h layout: quad c0 -> ushort offset (c0&63)*2 + (c0>>6)*4
        #pragma unroll
        for (int nt = 0; nt < 8; ++nt) {
            const float4 bq = *(const float4*)&sB2[nt * 16 + lg * 4];
            ushort4 st;
            st.x = f2bf(acc2[nt][0] + bq.x);
            st.y = f2bf(acc2[nt][1] + bq.y);
            st.z = f2bf(acc2[nt][2] + bq.z);
            st.w = f2bf(acc2[nt][3] + bq.w);
            const int c0   = nt * 16 + lg * 4;
            const int soff = ((c0 & 63) << 1) + ((c0 >> 6) << 2);
            *(ushort4*)&h[(size_t)(chunk + lm) * DOUT + soff] = st;
        }
    }
}

// ---------------------------------------------------------------------------
// Gather: out[p,:] = up[p,:] + mean_k h_bf16[idx[p,k]*8 + n, :]
//
// R7: quarter-wave-per-row. Lane (q=lane>>4, lq=lane&15); group g covers 4
// rows (one per quarter). Per group: 3 x uint4 h-row gathers (1 KB/instr,
// 16 B/lane via the swizzled h layout) + 2 dense f32x4 up loads + 2 stores
// = 7 VMEM instr / 4 rows (was 10, with 512 B gathers). Explicit 2-deep
// A/B load pipeline (named buffers, fully unrolled). idx preloaded
// lane-owned + __shfl. launch_bounds(256,8) pins VGPR<=64 for 32 waves/CU.
// ---------------------------------------------------------------------------
#define LOADG(g, g0, g1, g2, u0, u1, row) do {                               \
    const int rr_ = (g) * 4 + q;                                             \
    row = base + rr_;                                                        \
    const int n_  = rr_ & 7;                       /* base % 8 == 0 */       \
    const int i0_ = __shfl(mi0, rr_);                                        \
    const int i1_ = __shfl(mi1, rr_);                                        \
    const int i2_ = __shfl(mi2, rr_);                                        \
    g0 = hq[(unsigned)(i0_ * 8 + n_) * 16u + lq];                            \
    g1 = hq[(unsigned)(i1_ * 8 + n_) * 16u + lq];                            \
    g2 = hq[(unsigned)(i2_ * 8 + n_) * 16u + lq];                            \
    u0 = __builtin_nontemporal_load(&upv[row * 32 + lq]);                    \
    u1 = __builtin_nontemporal_load(&upv[row * 32 + 16 + lq]);               \
} while (0)

#define CONSUME(g0, g1, g2, u0, u1, row) do {                                \
    float s0 = 0.f, s1 = 0.f, s2 = 0.f, s3 = 0.f;                            \
    float s4 = 0.f, s5 = 0.f, s6 = 0.f, s7 = 0.f;                            \
    const u32x4 ga_[3] = {g0, g1, g2};                                       \
    _Pragma("unroll")                                                        \
    for (int j = 0; j < 3; ++j) {                                            \
        const u32x4 v = ga_[j];                                              \
        s0 += __uint_as_float(v.x << 16);                                    \
        s1 += __uint_as_float(v.x & 0xffff0000u);                            \
        s2 += __uint_as_float(v.y << 16);                                    \
        s3 += __uint_as_float(v.y & 0xffff0000u);                            \
        s4 += __uint_as_float(v.z << 16);                                    \
        s5 += __uint_as_float(v.z & 0xffff0000u);                            \
        s6 += __uint_as_float(v.w << 16);                                    \
        s7 += __uint_as_float(v.w & 0xffff0000u);                            \
    }                                                                        \
    f32x4 o0, o1;                                                            \
    o0.x = u0.x + s0 * (1.0f / 3.0f);                                        \
    o0.y = u0.y + s1 * (1.0f / 3.0f);                                        \
    o0.z = u0.z + s2 * (1.0f / 3.0f);                                        \
    o0.w = u0.w + s3 * (1.0f / 3.0f);                                        \
    o1.x = u1.x + s4 * (1.0f / 3.0f);                                        \
    o1.y = u1.y + s5 * (1.0f / 3.0f);                                        \
    o1.z = u1.z + s6 * (1.0f / 3.0f);                                        \
    o1.w = u1.w + s7 * (1.0f / 3.0f);                                        \
    __builtin_nontemporal_store(o0, &outv[row * 32 + lq]);                   \
    __builtin_nontemporal_store(o1, &outv[row * 32 + 16 + lq]);              \
} while (0)

__global__ __launch_bounds__(256, 8) void knn_gather(
    const float* __restrict__ up, const int* __restrict__ idx,
    const u32x4* __restrict__ hq, float* __restrict__ out)
{
    const int wave = threadIdx.x >> 6, lane = threadIdx.x & 63;
    const int q = lane >> 4, lq = lane & 15;
    const long long wid  = (long long)blockIdx.x * 4 + wave;   // 8192 waves
    const long long base = wid * 64;                           // rows/wave

    // lane l owns the 3 neighbor indices of row (base + l)
    const int* ip = idx + (base + lane) * 3;
    const int mi0 = ip[0], mi1 = ip[1], mi2 = ip[2];

    const f32x4* upv  = (const f32x4*)up;       // up row = 32 f32x4 (512 B)
    f32x4*       outv = (f32x4*)out;

    u32x4 gA0, gA1, gA2, gB0, gB1, gB2;
    f32x4 uA0, uA1, uB0, uB1;
    long long rowA, rowB;

    LOADG(0, gA0, gA1, gA2, uA0, uA1, rowA);
    #pragma unroll
    for (int g = 0; g < 16; g += 2) {
        LOADG(g + 1, gB0, gB1, gB2, uB0, uB1, rowB);
        CONSUME(gA0, gA1, gA2, uA0, uA1, rowA);
        if (g + 2 < 16) LOADG(g + 2, gA0, gA1, gA2, uA0, uA1, rowA);
        CONSUME(gB0, gB1, gB2, uB0, uB1, rowB);
    }
}

// ---------------------------------------------------------------------------
extern "C" void kernel_launch(void* const* d_in, const int* in_sizes, int n_in,
                              void* d_out, int out_size, void* d_ws, size_t ws_size,
                              hipStream_t stream)
{
    const float* down = (const float*)d_in[0];
    const float* up   = (const float*)d_in[1];
    const int*   idx  = (const int*)d_in[2];
    const float* W1   = (const float*)d_in[3];
    const float* b1   = (const float*)d_in[4];
    const float* W2   = (const float*)d_in[5];
    const float* b2   = (const float*)d_in[6];
    float* out = (float*)d_out;
    unsigned short* h = (unsigned short*)d_ws;   // M_ x 128 bf16 = 32 MiB

    knn_mlp_mfma<<<256, 512, 0, stream>>>(down, W1, b1, W2, b2, h);
    knn_gather<<<2048, 256, 0, stream>>>(up, idx, (const u32x4*)h, out);
}

// Round 8
// 556.618 us; speedup vs baseline: 1.0126x; 1.0126x over previous
//
#include <hip/hip_runtime.h>

#define LD_   16384
#define LU_   65536
#define N_    8
#define DIN   256
#define DOUT  128
#define K_    3
#define M_    (LD_ * N_)   // 131072 rows through the MLP

typedef short bf16x8 __attribute__((ext_vector_type(8)));
typedef float f32x4  __attribute__((ext_vector_type(4)));
typedef unsigned int u32x2 __attribute__((ext_vector_type(2)));

// fp32 -> bf16 round-to-nearest-even (inputs finite, no NaN handling)
__device__ __forceinline__ unsigned short f2bf(float f) {
    unsigned int x = __float_as_uint(f);
    x += 0x7fffu + ((x >> 16) & 1u);
    return (unsigned short)(x >> 16);
}

__device__ __forceinline__ bf16x8 ld_bf16x8(const unsigned short* p) {
    // two aligned 8 B LDS reads (b64); p is 8 B aligned by construction
    const short4 lo = *(const short4*)p;
    const short4 hi = *(const short4*)(p + 4);
    bf16x8 r = {lo.x, lo.y, lo.z, lo.w, hi.x, hi.y, hi.z, hi.w};
    return r;
}

// LDS strides (bf16 elements); S/2 mod 32 == 2 -> conflict-free b64 frag reads
#define W1_STRIDE 260   // 130 words == 2 (mod 32); row base 520 B, 8 B-aligned
#define W2_STRIDE 132   //  66 words == 2 (mod 32)
#define H1_STRIDE 132   //  66 words == 2 (mod 32)

// ---------------------------------------------------------------------------
// MLP: h[m,:] = relu(down[m,:] @ W1 + b1) @ W2 + b2, h stored as bf16.
// 256 blocks x 512 threads (1 block/CU, 132 KiB LDS), 4 passes of 128 rows.
// Swapped-operand MFMA (D = W^T . x^T): lane lm = row, regs = 4 consecutive
// output features -> packed ds_write_b64 / 8 B h-stores. Per-wave-private sH
// -> no per-pass barriers. Down rows prefetched across passes; pass-0 loads
// issued before W staging. Fabric traffic 168 MB -> ~26 us floor; measured
// ~30 (R5 calibration) — at floor.
// ---------------------------------------------------------------------------
__global__ __launch_bounds__(512, 2) void knn_mlp_mfma(
    const float* __restrict__ down, const float* __restrict__ W1,
    const float* __restrict__ b1,   const float* __restrict__ W2,
    const float* __restrict__ b2,   unsigned short* __restrict__ h)
{
    __shared__ unsigned short sW1t[DOUT * W1_STRIDE];        // [n][k] 65 KiB
    __shared__ unsigned short sW2t[DOUT * W2_STRIDE];        // [n][k] 33 KiB
    __shared__ unsigned short sH[8][16 * H1_STRIDE];         // per-wave 33 KiB
    __shared__ float sB1[DOUT], sB2[DOUT];                   // 1 KiB

    const int tid  = threadIdx.x;
    const int wave = tid >> 6, lane = tid & 63;
    const int lm = lane & 15, lg = lane >> 4;

    const int row0 = blockIdx.x * 512 + wave * 16;           // pass adds 128
    const float* dbase = down + (size_t)(row0 + lm) * DIN + lg * 8;

    // ---- issue pass-0 row loads FIRST: they fly under the W staging ----
    float4 raw[16];
    #pragma unroll
    for (int k = 0; k < 8; ++k) {
        raw[2 * k]     = *(const float4*)(dbase + k * 32);
        raw[2 * k + 1] = *(const float4*)(dbase + k * 32 + 4);
    }

    // ---- stage W1^T (bf16, transposed) ----
    #pragma unroll
    for (int it = 0; it < 16; ++it) {
        const int fid = it * 512 + tid;              // 8192 float4s of W1
        const int k = fid >> 5, n4 = (fid & 31) * 4;
        const float4 w = ((const float4*)W1)[fid];
        sW1t[(n4 + 0) * W1_STRIDE + k] = f2bf(w.x);
        sW1t[(n4 + 1) * W1_STRIDE + k] = f2bf(w.y);
        sW1t[(n4 + 2) * W1_STRIDE + k] = f2bf(w.z);
        sW1t[(n4 + 3) * W1_STRIDE + k] = f2bf(w.w);
    }
    // ---- stage W2^T ----
    #pragma unroll
    for (int it = 0; it < 8; ++it) {
        const int fid = it * 512 + tid;              // 4096 float4s of W2
        const int k = fid >> 5, n4 = (fid & 31) * 4;
        const float4 w = ((const float4*)W2)[fid];
        sW2t[(n4 + 0) * W2_STRIDE + k] = f2bf(w.x);
        sW2t[(n4 + 1) * W2_STRIDE + k] = f2bf(w.y);
        sW2t[(n4 + 2) * W2_STRIDE + k] = f2bf(w.z);
        sW2t[(n4 + 3) * W2_STRIDE + k] = f2bf(w.w);
    }
    // ---- stage biases (f32, 128 each) ----
    if (tid < 32)      ((float4*)sB1)[tid]      = ((const float4*)b1)[tid];
    else if (tid < 64) ((float4*)sB2)[tid - 32] = ((const float4*)b2)[tid - 32];
    __syncthreads();   // the ONLY workgroup barrier: weights staged

    unsigned short* hw = sH[wave];

    #pragma unroll
    for (int pass = 0; pass < 4; ++pass) {
        const int chunk = row0 + pass * 128;

        // convert in-flight rows to B-frags (down^T); raw regs then free
        bf16x8 A[8];
        #pragma unroll
        for (int k = 0; k < 8; ++k) {
            const float4 r0 = raw[2 * k], r1 = raw[2 * k + 1];
            const bf16x8 a = {(short)f2bf(r0.x), (short)f2bf(r0.y), (short)f2bf(r0.z), (short)f2bf(r0.w),
                              (short)f2bf(r1.x), (short)f2bf(r1.y), (short)f2bf(r1.z), (short)f2bf(r1.w)};
            A[k] = a;
        }

        // issue next pass's 16 loads: they fly under the MFMAs
        if (pass < 3) {
            const float* dp = dbase + (size_t)(pass + 1) * 128 * DIN;
            #pragma unroll
            for (int k = 0; k < 8; ++k) {
                raw[2 * k]     = *(const float4*)(dp + k * 32);
                raw[2 * k + 1] = *(const float4*)(dp + k * 32 + 4);
            }
        }

        // layer 1: D1 = W1^T . down^T  (lane: m=lm, n1=nt*16+lg*4+i)
        f32x4 acc[8];
        #pragma unroll
        for (int nt = 0; nt < 8; ++nt) acc[nt] = (f32x4){0.f, 0.f, 0.f, 0.f};
        #pragma unroll
        for (int k = 0; k < 8; ++k) {
            const int koff = k * 32 + lg * 8;
            #pragma unroll
            for (int nt = 0; nt < 8; ++nt) {
                const bf16x8 Wf = ld_bf16x8(&sW1t[(nt * 16 + lm) * W1_STRIDE + koff]);
                acc[nt] = __builtin_amdgcn_mfma_f32_16x16x32_bf16(Wf, A[k], acc[nt], 0, 0, 0);
            }
        }

        // relu + bias -> per-wave LDS tile, packed ds_write_b64
        #pragma unroll
        for (int nt = 0; nt < 8; ++nt) {
            const float4 bq = *(const float4*)&sB1[nt * 16 + lg * 4];
            ushort4 st;
            st.x = f2bf(fmaxf(acc[nt][0] + bq.x, 0.0f));
            st.y = f2bf(fmaxf(acc[nt][1] + bq.y, 0.0f));
            st.z = f2bf(fmaxf(acc[nt][2] + bq.z, 0.0f));
            st.w = f2bf(fmaxf(acc[nt][3] + bq.w, 0.0f));
            *(ushort4*)&hw[lm * H1_STRIDE + nt * 16 + lg * 4] = st;
        }
        // wave-local write->read ordering on the private sH tile
        asm volatile("s_waitcnt lgkmcnt(0)" ::: "memory");

        // layer 2: D2 = W2^T . h1^T  (lane: m=lm, n2=nt*16+lg*4+i)
        f32x4 acc2[8];
        #pragma unroll
        for (int nt = 0; nt < 8; ++nt) acc2[nt] = (f32x4){0.f, 0.f, 0.f, 0.f};
        #pragma unroll
        for (int ks = 0; ks < 4; ++ks) {
            const int koff = ks * 32 + lg * 8;
            const bf16x8 Bh = ld_bf16x8(&hw[lm * H1_STRIDE + koff]);
            #pragma unroll
            for (int nt = 0; nt < 8; ++nt) {
                const bf16x8 Wf = ld_bf16x8(&sW2t[(nt * 16 + lm) * W2_STRIDE + koff]);
                acc2[nt] = __builtin_amdgcn_mfma_f32_16x16x32_bf16(Wf, Bh, acc2[nt], 0, 0, 0);
            }
        }

        // epilogue: + b2, cvt bf16, packed 8 B stores (plain row-major h)
        #pragma unroll
        for (int nt = 0; nt < 8; ++nt) {
            const float4 bq = *(const float4*)&sB2[nt * 16 + lg * 4];
            ushort4 st;
            st.x = f2bf(acc2[nt][0] + bq.x);
            st.y = f2bf(acc2[nt][1] + bq.y);
            st.z = f2bf(acc2[nt][2] + bq.z);
            st.w = f2bf(acc2[nt][3] + bq.w);
            *(ushort4*)&h[(size_t)(chunk + lm) * DOUT + nt * 16 + lg * 4] = st;
        }
    }
}

// ---------------------------------------------------------------------------
// Gather: out[p,:] = up[p,:] + mean_k h_bf16[idx[p,k]*8 + n, :]
// Best-verified structure (R3/R4): idx preloaded lane-owned + __shfl,
// half-wave-per-pair (2 random 256 B h segments/instr — the measured sweet
// spot: 1 seg/instr (R1) and 4 seg/instr (R7) are both slower), f32x4
// nontemporal up/out, u32x2 h gathers. Standalone kernel for full TLP
// (fused 8-wave/CU version loses ~35 us — R5).
// Fabric traffic: up 268 + out 268 + h 402 (LLC) + idx 6 = 944 MB ->
// ~145 us floor at the ~6.5 TB/s delivery ceiling; measured ~140 — AT floor.
// ---------------------------------------------------------------------------
__global__ __launch_bounds__(256) void knn_gather(
    const float* __restrict__ up, const int* __restrict__ idx,
    const unsigned int* __restrict__ h32, float* __restrict__ out)
{
    const int wave = threadIdx.x >> 6, lane = threadIdx.x & 63;
    const int half = lane >> 5, lih = lane & 31;
    const long long wid  = (long long)blockIdx.x * 4 + wave;   // 8192 waves
    const long long base = wid * 64;                           // pairs/wave

    // lane l owns the 3 neighbor indices of pair (base + l)
    const int* ip = idx + (base + lane) * 3;
    const int mi0 = ip[0], mi1 = ip[1], mi2 = ip[2];

    const u32x2* hg   = (const u32x2*)h32;      // h row = 32 uint2 (256 B)
    const f32x4* upv  = (const f32x4*)up;       // up row = 32 float4 (512 B)
    f32x4*       outv = (f32x4*)out;

    #pragma unroll
    for (int gb = 0; gb < 8; ++gb) {            // 8 batches x 4 groups x 2 pairs
        u32x2 ga[4][3];
        f32x4 uu[4];
        int   pp[4];
        #pragma unroll
        for (int u = 0; u < 4; ++u) {
            const int p = (gb * 4 + u) * 2 + half;     // pair-in-wave 0..63
            pp[u] = p;
            const int i0 = __shfl(mi0, p);
            const int i1 = __shfl(mi1, p);
            const int i2 = __shfl(mi2, p);
            const int n  = p & 7;                      // base % 8 == 0
            ga[u][0] = hg[(unsigned)(i0 * 8 + n) * 32u + lih];
            ga[u][1] = hg[(unsigned)(i1 * 8 + n) * 32u + lih];
            ga[u][2] = hg[(unsigned)(i2 * 8 + n) * 32u + lih];
            uu[u] = __builtin_nontemporal_load(&upv[(base + p) * 32 + lih]);
        }
        #pragma unroll
        for (int u = 0; u < 4; ++u) {
            float s0 = 0.f, s1 = 0.f, s2 = 0.f, s3 = 0.f;
            #pragma unroll
            for (int j = 0; j < 3; ++j) {
                const u32x2 v = ga[u][j];
                s0 += __uint_as_float(v.x << 16);
                s1 += __uint_as_float(v.x & 0xffff0000u);
                s2 += __uint_as_float(v.y << 16);
                s3 += __uint_as_float(v.y & 0xffff0000u);
            }
            f32x4 o;
            o.x = uu[u].x + s0 * (1.0f / 3.0f);
            o.y = uu[u].y + s1 * (1.0f / 3.0f);
            o.z = uu[u].z + s2 * (1.0f / 3.0f);
            o.w = uu[u].w + s3 * (1.0f / 3.0f);
            __builtin_nontemporal_store(o, &outv[(base + pp[u]) * 32 + lih]);
        }
    }
}

// ---------------------------------------------------------------------------
extern "C" void kernel_launch(void* const* d_in, const int* in_sizes, int n_in,
                              void* d_out, int out_size, void* d_ws, size_t ws_size,
                              hipStream_t stream)
{
    const float* down = (const float*)d_in[0];
    const float* up   = (const float*)d_in[1];
    const int*   idx  = (const int*)d_in[2];
    const float* W1   = (const float*)d_in[3];
    const float* b1   = (const float*)d_in[4];
    const float* W2   = (const float*)d_in[5];
    const float* b2   = (const float*)d_in[6];
    float* out = (float*)d_out;
    unsigned short* h = (unsigned short*)d_ws;   // M_ x 128 bf16 = 32 MiB

    knn_mlp_mfma<<<256, 512, 0, stream>>>(down, W1, b1, W2, b2, h);
    knn_gather<<<2048, 256, 0, stream>>>(up, idx, (const unsigned int*)h, out);
}